// Round 2
// baseline (241.586 us; speedup 1.0000x reference)
//
#include <hip/hip_runtime.h>
#include <stdint.h>
#include <stddef.h>

// Reference collapse:
//   softmax over k sums to 1 and the einsum applies it pointwise to v,
//   so out = conv1x1(conv1x1(x, W_v, b_v), W_proj, b_proj)
//          = (W_proj @ W_v) @ x  + (W_proj @ b_v + b_proj)
// One 192x192 bf16-MFMA GEMM over 8*16384 pixels. Memory-bound (~201 MB).
//
// v3: kill the per-tile vmcnt(0) store drain.
//   - __syncthreads() lowers to "s_waitcnt vmcnt(0) lgkmcnt(0); s_barrier",
//     putting the 48KB/tile store retirement on every tile's critical path.
//     Replaced with lgkmcnt(0)-only + raw s_barrier: the barrier only needs
//     to order LDS writes vs reads; global stores drain lazily across tiles.
//   - 3-bit XOR swizzle on the 16B LDS block index (blk ^= (row>>2)&7),
//     same function on write and read: kills the 8-way staging-write bank
//     conflict (1600B lane stride -> bank delta 16 -> 2 banks for 16 lanes).
//   - T_TILES=2, grid 1024 -> 3 blocks/CU resident (LDS 51.2KB caps at 3).

#define CDIM 192
#define HWPX 16384
#define LDS_STRIDE 200  // 192 + 8 pad (ushorts); keeps row-term bank spread
#define T_TILES 2       // tiles per block; grid = 2048/2 = 1024 = 4/CU, 3 resident

typedef __attribute__((ext_vector_type(8))) short short8;
typedef __attribute__((ext_vector_type(4))) float floatx4;
typedef __attribute__((ext_vector_type(4))) unsigned short ushort4_t;

__device__ __forceinline__ unsigned short f2bf(float f) {
    union { float f; unsigned int u; } v; v.f = f;
    unsigned int r = (v.u + 0x7FFFu + ((v.u >> 16) & 1u)) >> 16;  // RTNE
    return (unsigned short)r;
}

// LDS-only barrier: order ds_write -> ds_read across the workgroup WITHOUT
// draining the vmem queue (stores keep retiring in the background).
__device__ __forceinline__ void lds_barrier() {
    asm volatile("s_waitcnt lgkmcnt(0)" ::: "memory");
    __builtin_amdgcn_sched_barrier(0);
    __builtin_amdgcn_s_barrier();
}

// ---- prep: M = W_proj @ W_v (bf16), bias = W_proj @ b_v + b_proj ----
__global__ __launch_bounds__(192) void prep_kernel(
    const float* __restrict__ w_qkv, const float* __restrict__ b_qkv,
    const float* __restrict__ w_proj, const float* __restrict__ b_proj,
    unsigned short* __restrict__ Mb, float* __restrict__ bias)
{
    const int o = blockIdx.x, c = threadIdx.x;
    const float* wpr = w_proj + o * CDIM;
    const float* wv  = w_qkv + 2 * CDIM * CDIM;  // v-rows of w_qkv
    float acc = 0.f;
    #pragma unroll 32
    for (int k = 0; k < CDIM; ++k)
        acc = fmaf(wpr[k], wv[k * CDIM + c], acc);
    Mb[o * CDIM + c] = f2bf(acc);

    __shared__ float red[CDIM];
    red[c] = wpr[c] * b_qkv[2 * CDIM + c];
    __syncthreads();
    if (c < 64) {
        float v = red[c] + red[c + 64] + red[c + 128];
        #pragma unroll
        for (int off = 32; off > 0; off >>= 1) v += __shfl_down(v, off);
        if (c == 0) bias[o] = v + b_proj[o];
    }
}

// ---- main: out[b, :, p0:p0+64] = M @ x[b, :, p0:p0+64] + bias ----
__global__ __launch_bounds__(256, 3) void fused_kernel(
    const float* __restrict__ x,
    const unsigned short* __restrict__ Mb,
    const float* __restrict__ bias,
    float* __restrict__ out)
{
    __shared__ __align__(16) unsigned short Xl[2][64 * LDS_STRIDE];  // 2 x 25.6 KB

    const int tid  = threadIdx.x;
    const int lane = tid & 63;
    const int w    = tid >> 6;    // wave 0..3
    const int n    = lane & 15;   // MFMA n / m-lane index
    const int q    = lane >> 4;   // MFMA quad

    // staging geometry: p4 = tid&15 (4-px group), cg0 = tid>>4 (4-ch group base)
    const int p4  = tid & 15;
    const int cg0 = tid >> 4;

    const int tile0 = blockIdx.x * T_TILES;

    // issue the 12 float4 loads of one tile into registers (no wait here)
    auto load_tile = [&](int tile, floatx4* fl) {
        const float* xb = x + (size_t)(tile >> 8) * (CDIM * HWPX)
                            + ((tile & 255) << 6);
        const float* src0 = xb + (size_t)(cg0 * 4) * HWPX + p4 * 4;
        #pragma unroll
        for (int it = 0; it < 3; ++it) {
            const float* src = src0 + (size_t)(it * 64) * HWPX;
            #pragma unroll
            for (int j = 0; j < 4; ++j)
                fl[it * 4 + j] = *(const floatx4*)(src + (size_t)j * HWPX);
        }
    };

    // convert fp32 -> bf16 and write transposed [p][c^swz] into LDS buffer.
    // swizzle: 16B-block index XORed with (row>>2)&7; row = p4*4+i so the
    // swizzle operand is p4 (constant across i) -> compute column once.
    auto stage_tile = [&](int buf, const floatx4* fl) {
        const int sw = (p4 & 7) << 3;   // (row>>2)&7 == p4&7, in ushort units
        #pragma unroll
        for (int it = 0; it < 3; ++it) {
            unsigned short* dst =
                &Xl[buf][(p4 * 4) * LDS_STRIDE + (((it * 16 + cg0) * 4) ^ sw)];
            #pragma unroll
            for (int i = 0; i < 4; ++i) {
                ushort4_t v4;
                v4.x = f2bf(fl[it * 4 + 0][i]);
                v4.y = f2bf(fl[it * 4 + 1][i]);
                v4.z = f2bf(fl[it * 4 + 2][i]);
                v4.w = f2bf(fl[it * 4 + 3][i]);
                *(ushort4_t*)(dst + i * LDS_STRIDE) = v4;
            }
        }
    };

    // hoisted A fragments (wave w covers output channels [w*48, w*48+48))
    short8 a[3][6];
    float  bo[3][4];
    #pragma unroll
    for (int t = 0; t < 3; ++t) {
        const int ot = w * 3 + t;
        const unsigned short* arow = Mb + (ot * 16 + n) * CDIM + q * 8;
        #pragma unroll
        for (int ks = 0; ks < 6; ++ks)        // A[m=lane&15][k=quad*8+j]
            a[t][ks] = *(const short8*)(arow + ks * 32);
        #pragma unroll
        for (int r = 0; r < 4; ++r)
            bo[t][r] = bias[ot * 16 + q * 4 + r];
    }

    floatx4 fl[12];

    // prologue: stage tile 0
    load_tile(tile0, fl);
    stage_tile(0, fl);
    lds_barrier();

    #pragma unroll
    for (int t = 0; t < T_TILES; ++t) {
        const int cur = t & 1;

        // issue next tile's loads FIRST — HBM latency hides under MFMA+stores
        if (t + 1 < T_TILES)
            load_tile(tile0 + t + 1, fl);

        // compute tile t from Xl[cur]
        floatx4 acc[3][4];
        #pragma unroll
        for (int tt = 0; tt < 3; ++tt)
            #pragma unroll
            for (int pt = 0; pt < 4; ++pt)
                acc[tt][pt] = (floatx4){0.f, 0.f, 0.f, 0.f};

        #pragma unroll
        for (int pt = 0; pt < 4; ++pt) {
            const int row = pt * 16 + n;
            const int sw  = ((row >> 2) & 7) << 3;
            const unsigned short* rbase = &Xl[cur][row * LDS_STRIDE];
            short8 bfr[6];
            #pragma unroll
            for (int ks = 0; ks < 6; ++ks)    // B[k=quad*8+j][n=lane&15]
                bfr[ks] = *(const short8*)(rbase + ((q * 8 + ks * 32) ^ sw));
            #pragma unroll
            for (int tt = 0; tt < 3; ++tt)
                #pragma unroll
                for (int ks = 0; ks < 6; ++ks)
                    acc[tt][pt] = __builtin_amdgcn_mfma_f32_16x16x32_bf16(
                        a[tt][ks], bfr[ks], acc[tt][pt], 0, 0, 0);
        }

        // store tile t: D row = q*4 + r, col = n
        {
            const int tile = tile0 + t;
            float* ob = out + (size_t)(tile >> 8) * (CDIM * HWPX)
                            + ((tile & 255) << 6);
            #pragma unroll
            for (int tt = 0; tt < 3; ++tt) {
                #pragma unroll
                for (int r = 0; r < 4; ++r) {
                    const int o = (w * 3 + tt) * 16 + q * 4 + r;
                    float* orow = ob + (size_t)o * HWPX + n;
                    #pragma unroll
                    for (int pt = 0; pt < 4; ++pt)
                        orow[pt * 16] = acc[tt][pt][r] + bo[tt][r];
                }
            }
        }

        // consume the prefetch: compiler waits the counted vmcnt for fl[]
        // (loads are OLDEST in the FIFO, so they retire without waiting on
        // this tile's stores), then LDS-only barrier — no store drain.
        if (t + 1 < T_TILES)
            stage_tile(cur ^ 1, fl);

        lds_barrier();
    }
}

extern "C" void kernel_launch(void* const* d_in, const int* in_sizes, int n_in,
                              void* d_out, int out_size, void* d_ws, size_t ws_size,
                              hipStream_t stream) {
    const float* x      = (const float*)d_in[0];
    const float* w_qkv  = (const float*)d_in[1];
    const float* b_qkv  = (const float*)d_in[2];
    // d_in[3] = w_attn, d_in[4] = b_attn: mathematically unused (softmax sums to 1)
    const float* w_proj = (const float*)d_in[5];
    const float* b_proj = (const float*)d_in[6];
    float* out = (float*)d_out;

    unsigned short* Mb = (unsigned short*)d_ws;                       // 192*192 bf16
    float* bias = (float*)((char*)d_ws + CDIM * CDIM * sizeof(unsigned short));

    const int B = in_sizes[0] / (CDIM * HWPX);  // 8

    prep_kernel<<<CDIM, CDIM, 0, stream>>>(w_qkv, b_qkv, w_proj, b_proj, Mb, bias);
    fused_kernel<<<(B * 256) / T_TILES, 256, 0, stream>>>(x, Mb, bias, out);
}

// Round 3
// 225.402 us; speedup vs baseline: 1.0718x; 1.0718x over previous
//
#include <hip/hip_runtime.h>
#include <stdint.h>
#include <stddef.h>

// Reference collapse:
//   softmax over k sums to 1 and the einsum applies it pointwise to v,
//   so out = conv1x1(conv1x1(x, W_v, b_v), W_proj, b_proj)
//          = (W_proj @ W_v) @ x  + (W_proj @ b_v + b_proj)
// One 192x192 bf16-MFMA GEMM over 8*16384 pixels. Memory-bound (~201 MB).
//
// v4: revert v3's lazy store drain — it DOUBLED HBM traffic (WRITE 98->197MB,
//   FETCH 50->102MB). Undrained 64B partial-line stores from ~3 blocks/CU
//   x 32 CUs ~= L2 capacity per XCD; dirty lines evicted between the two
//   half-line stores -> every out line written to HBM twice, and the 2x
//   write stream evicted x from L3. __syncthreads()'s vmcnt(0) drain was
//   acting as write-burst flow control. Restored.
//   Kept from v3: XOR LDS swizzle (bank conflicts 3.54M->1.18M), register
//   prefetch of tile t+1, T_TILES=2 / grid 1024 (3 blocks/CU by LDS).

#define CDIM 192
#define HWPX 16384
#define LDS_STRIDE 200  // 192 + 8 pad (ushorts)
#define T_TILES 2       // tiles per block; grid = 2048/2 = 1024

typedef __attribute__((ext_vector_type(8))) short short8;
typedef __attribute__((ext_vector_type(4))) float floatx4;
typedef __attribute__((ext_vector_type(4))) unsigned short ushort4_t;

__device__ __forceinline__ unsigned short f2bf(float f) {
    union { float f; unsigned int u; } v; v.f = f;
    unsigned int r = (v.u + 0x7FFFu + ((v.u >> 16) & 1u)) >> 16;  // RTNE
    return (unsigned short)r;
}

// ---- prep: M = W_proj @ W_v (bf16), bias = W_proj @ b_v + b_proj ----
__global__ __launch_bounds__(192) void prep_kernel(
    const float* __restrict__ w_qkv, const float* __restrict__ b_qkv,
    const float* __restrict__ w_proj, const float* __restrict__ b_proj,
    unsigned short* __restrict__ Mb, float* __restrict__ bias)
{
    const int o = blockIdx.x, c = threadIdx.x;
    const float* wpr = w_proj + o * CDIM;
    const float* wv  = w_qkv + 2 * CDIM * CDIM;  // v-rows of w_qkv
    float acc = 0.f;
    #pragma unroll 32
    for (int k = 0; k < CDIM; ++k)
        acc = fmaf(wpr[k], wv[k * CDIM + c], acc);
    Mb[o * CDIM + c] = f2bf(acc);

    __shared__ float red[CDIM];
    red[c] = wpr[c] * b_qkv[2 * CDIM + c];
    __syncthreads();
    if (c < 64) {
        float v = red[c] + red[c + 64] + red[c + 128];
        #pragma unroll
        for (int off = 32; off > 0; off >>= 1) v += __shfl_down(v, off);
        if (c == 0) bias[o] = v + b_proj[o];
    }
}

// ---- main: out[b, :, p0:p0+64] = M @ x[b, :, p0:p0+64] + bias ----
__global__ __launch_bounds__(256, 3) void fused_kernel(
    const float* __restrict__ x,
    const unsigned short* __restrict__ Mb,
    const float* __restrict__ bias,
    float* __restrict__ out)
{
    __shared__ __align__(16) unsigned short Xl[2][64 * LDS_STRIDE];  // 2 x 25.6 KB

    const int tid  = threadIdx.x;
    const int lane = tid & 63;
    const int w    = tid >> 6;    // wave 0..3
    const int n    = lane & 15;   // MFMA n / m-lane index
    const int q    = lane >> 4;   // MFMA quad

    // staging geometry: p4 = tid&15 (4-px group), cg0 = tid>>4 (4-ch group base)
    const int p4  = tid & 15;
    const int cg0 = tid >> 4;

    const int tile0 = blockIdx.x * T_TILES;

    // issue the 12 float4 loads of one tile into registers (no wait here)
    auto load_tile = [&](int tile, floatx4* fl) {
        const float* xb = x + (size_t)(tile >> 8) * (CDIM * HWPX)
                            + ((tile & 255) << 6);
        const float* src0 = xb + (size_t)(cg0 * 4) * HWPX + p4 * 4;
        #pragma unroll
        for (int it = 0; it < 3; ++it) {
            const float* src = src0 + (size_t)(it * 64) * HWPX;
            #pragma unroll
            for (int j = 0; j < 4; ++j)
                fl[it * 4 + j] = *(const floatx4*)(src + (size_t)j * HWPX);
        }
    };

    // convert fp32 -> bf16 and write transposed [p][c^swz] into LDS buffer.
    // swizzle: 16B-block index XORed with (row>>2)&7; row = p4*4+i so the
    // swizzle operand is p4 (constant across i) -> compute column once.
    auto stage_tile = [&](int buf, const floatx4* fl) {
        const int sw = (p4 & 7) << 3;   // (row>>2)&7 == p4&7, in ushort units
        #pragma unroll
        for (int it = 0; it < 3; ++it) {
            unsigned short* dst =
                &Xl[buf][(p4 * 4) * LDS_STRIDE + (((it * 16 + cg0) * 4) ^ sw)];
            #pragma unroll
            for (int i = 0; i < 4; ++i) {
                ushort4_t v4;
                v4.x = f2bf(fl[it * 4 + 0][i]);
                v4.y = f2bf(fl[it * 4 + 1][i]);
                v4.z = f2bf(fl[it * 4 + 2][i]);
                v4.w = f2bf(fl[it * 4 + 3][i]);
                *(ushort4_t*)(dst + i * LDS_STRIDE) = v4;
            }
        }
    };

    // hoisted A fragments (wave w covers output channels [w*48, w*48+48))
    short8 a[3][6];
    float  bo[3][4];
    #pragma unroll
    for (int t = 0; t < 3; ++t) {
        const int ot = w * 3 + t;
        const unsigned short* arow = Mb + (ot * 16 + n) * CDIM + q * 8;
        #pragma unroll
        for (int ks = 0; ks < 6; ++ks)        // A[m=lane&15][k=quad*8+j]
            a[t][ks] = *(const short8*)(arow + ks * 32);
        #pragma unroll
        for (int r = 0; r < 4; ++r)
            bo[t][r] = bias[ot * 16 + q * 4 + r];
    }

    floatx4 fl[12];

    // prologue: stage tile 0
    load_tile(tile0, fl);
    stage_tile(0, fl);
    __syncthreads();

    #pragma unroll
    for (int t = 0; t < T_TILES; ++t) {
        const int cur = t & 1;

        // issue next tile's loads FIRST — HBM latency hides under MFMA+stores
        if (t + 1 < T_TILES)
            load_tile(tile0 + t + 1, fl);

        // compute tile t from Xl[cur]
        floatx4 acc[3][4];
        #pragma unroll
        for (int tt = 0; tt < 3; ++tt)
            #pragma unroll
            for (int pt = 0; pt < 4; ++pt)
                acc[tt][pt] = (floatx4){0.f, 0.f, 0.f, 0.f};

        #pragma unroll
        for (int pt = 0; pt < 4; ++pt) {
            const int row = pt * 16 + n;
            const int sw  = ((row >> 2) & 7) << 3;
            const unsigned short* rbase = &Xl[cur][row * LDS_STRIDE];
            short8 bfr[6];
            #pragma unroll
            for (int ks = 0; ks < 6; ++ks)    // B[k=quad*8+j][n=lane&15]
                bfr[ks] = *(const short8*)(rbase + ((q * 8 + ks * 32) ^ sw));
            #pragma unroll
            for (int tt = 0; tt < 3; ++tt)
                #pragma unroll
                for (int ks = 0; ks < 6; ++ks)
                    acc[tt][pt] = __builtin_amdgcn_mfma_f32_16x16x32_bf16(
                        a[tt][ks], bfr[ks], acc[tt][pt], 0, 0, 0);
        }

        // store tile t: D row = q*4 + r, col = n
        {
            const int tile = tile0 + t;
            float* ob = out + (size_t)(tile >> 8) * (CDIM * HWPX)
                            + ((tile & 255) << 6);
            #pragma unroll
            for (int tt = 0; tt < 3; ++tt) {
                #pragma unroll
                for (int r = 0; r < 4; ++r) {
                    const int o = (w * 3 + tt) * 16 + q * 4 + r;
                    float* orow = ob + (size_t)o * HWPX + n;
                    #pragma unroll
                    for (int pt = 0; pt < 4; ++pt)
                        orow[pt * 16] = acc[tt][pt][r] + bo[tt][r];
                }
            }
        }

        // consume the prefetch (counted vmcnt wait for fl), then full
        // __syncthreads(): the vmcnt(0) drain doubles as store-burst flow
        // control — without it, dirty-line evictions double HBM writes (v3).
        if (t + 1 < T_TILES)
            stage_tile(cur ^ 1, fl);

        __syncthreads();
    }
}

extern "C" void kernel_launch(void* const* d_in, const int* in_sizes, int n_in,
                              void* d_out, int out_size, void* d_ws, size_t ws_size,
                              hipStream_t stream) {
    const float* x      = (const float*)d_in[0];
    const float* w_qkv  = (const float*)d_in[1];
    const float* b_qkv  = (const float*)d_in[2];
    // d_in[3] = w_attn, d_in[4] = b_attn: mathematically unused (softmax sums to 1)
    const float* w_proj = (const float*)d_in[5];
    const float* b_proj = (const float*)d_in[6];
    float* out = (float*)d_out;

    unsigned short* Mb = (unsigned short*)d_ws;                       // 192*192 bf16
    float* bias = (float*)((char*)d_ws + CDIM * CDIM * sizeof(unsigned short));

    const int B = in_sizes[0] / (CDIM * HWPX);  // 8

    prep_kernel<<<CDIM, CDIM, 0, stream>>>(w_qkv, b_qkv, w_proj, b_proj, Mb, bias);
    fused_kernel<<<(B * 256) / T_TILES, 256, 0, stream>>>(x, Mb, bias, out);
}

// Round 4
// 208.728 us; speedup vs baseline: 1.1574x; 1.0799x over previous
//
#include <hip/hip_runtime.h>
#include <stdint.h>
#include <stddef.h>

// Reference collapse:
//   softmax over k sums to 1 and the einsum applies it pointwise to v,
//   so out = conv1x1(conv1x1(x, W_v, b_v), W_proj, b_proj)
//          = (W_proj @ W_v) @ x  + (W_proj @ b_v + b_proj)
// One 192x192 bf16-MFMA GEMM over 8*16384 pixels. Memory-bound (~201 MB).
//
// v5: restore v2's traffic profile + counted-vmcnt pipelined barrier.
//   - v3/v4 traffic regression had TWO parts: lazy store drain (fixed in v4)
//     AND 3-blocks/CU residency at grid 1024 (96 blocks/XCD x ~48KB live
//     footprint > 4MB L2 -> thrash). Restored T_TILES=4 / grid 512 /
//     2 blocks/CU (v1 and v2 both measured 49.7+98.3 MB at this residency).
//   - Counted-vmcnt barrier WITH store drain: per tile,
//       compute -> stage(t+1) -> store(t) -> issue loads(t+2)
//       -> s_waitcnt vmcnt(12) lgkmcnt(0) -> s_barrier.
//     Loads issue AFTER stores, so vmcnt(12) (in-order retirement) drains
//     all 48 stores (v4's write flow control) while keeping the 12 loads of
//     tile t+2 in flight ACROSS the barrier: the load stream overlaps the
//     store drain instead of stopping at it.
//   - Single fl[12] register set (staged early, reloaded late in the same
//     iteration): depth-2 pipelining without 2x prefetch registers.
//   - Bias folded into accumulator init (acc = bias vector; no epilogue add).

#define CDIM 192
#define HWPX 16384
#define LDS_STRIDE 200  // 192 + 8 pad (ushorts)
#define T_TILES 4       // tiles per block; grid = 2048/4 = 512 = 2 blocks/CU

typedef __attribute__((ext_vector_type(8))) short short8;
typedef __attribute__((ext_vector_type(4))) float floatx4;
typedef __attribute__((ext_vector_type(4))) unsigned short ushort4_t;

__device__ __forceinline__ unsigned short f2bf(float f) {
    union { float f; unsigned int u; } v; v.f = f;
    unsigned int r = (v.u + 0x7FFFu + ((v.u >> 16) & 1u)) >> 16;  // RTNE
    return (unsigned short)r;
}

// ---- prep: M = W_proj @ W_v (bf16), bias = W_proj @ b_v + b_proj ----
__global__ __launch_bounds__(192) void prep_kernel(
    const float* __restrict__ w_qkv, const float* __restrict__ b_qkv,
    const float* __restrict__ w_proj, const float* __restrict__ b_proj,
    unsigned short* __restrict__ Mb, float* __restrict__ bias)
{
    const int o = blockIdx.x, c = threadIdx.x;
    const float* wpr = w_proj + o * CDIM;
    const float* wv  = w_qkv + 2 * CDIM * CDIM;  // v-rows of w_qkv
    float acc = 0.f;
    #pragma unroll 32
    for (int k = 0; k < CDIM; ++k)
        acc = fmaf(wpr[k], wv[k * CDIM + c], acc);
    Mb[o * CDIM + c] = f2bf(acc);

    __shared__ float red[CDIM];
    red[c] = wpr[c] * b_qkv[2 * CDIM + c];
    __syncthreads();
    if (c < 64) {
        float v = red[c] + red[c + 64] + red[c + 128];
        #pragma unroll
        for (int off = 32; off > 0; off >>= 1) v += __shfl_down(v, off);
        if (c == 0) bias[o] = v + b_proj[o];
    }
}

// ---- main: out[b, :, p0:p0+64] = M @ x[b, :, p0:p0+64] + bias ----
__global__ __launch_bounds__(256, 2) void fused_kernel(
    const float* __restrict__ x,
    const unsigned short* __restrict__ Mb,
    const float* __restrict__ bias,
    float* __restrict__ out)
{
    __shared__ __align__(16) unsigned short Xl[2][64 * LDS_STRIDE];  // 2 x 25.6 KB

    const int tid  = threadIdx.x;
    const int lane = tid & 63;
    const int w    = tid >> 6;    // wave 0..3
    const int n    = lane & 15;   // MFMA n / m-lane index
    const int q    = lane >> 4;   // MFMA quad

    // staging geometry: p4 = tid&15 (4-px group), cg0 = tid>>4 (4-ch group base)
    const int p4  = tid & 15;
    const int cg0 = tid >> 4;

    const int tile0 = blockIdx.x * T_TILES;

    // issue the 12 float4 loads of one tile into registers (no wait here)
    auto load_tile = [&](int tile, floatx4* fl) {
        const float* xb = x + (size_t)(tile >> 8) * (CDIM * HWPX)
                            + ((tile & 255) << 6);
        const float* src0 = xb + (size_t)(cg0 * 4) * HWPX + p4 * 4;
        #pragma unroll
        for (int it = 0; it < 3; ++it) {
            const float* src = src0 + (size_t)(it * 64) * HWPX;
            #pragma unroll
            for (int j = 0; j < 4; ++j)
                fl[it * 4 + j] = *(const floatx4*)(src + (size_t)j * HWPX);
        }
    };

    // convert fp32 -> bf16 and write transposed [p][c^swz] into LDS buffer.
    // swizzle: 16B-block index XORed with (row>>2)&7; row = p4*4+i so the
    // swizzle operand is p4 (constant across i) -> compute column once.
    auto stage_tile = [&](int buf, const floatx4* fl) {
        const int sw = (p4 & 7) << 3;   // (row>>2)&7 == p4&7, in ushort units
        #pragma unroll
        for (int it = 0; it < 3; ++it) {
            unsigned short* dst =
                &Xl[buf][(p4 * 4) * LDS_STRIDE + (((it * 16 + cg0) * 4) ^ sw)];
            #pragma unroll
            for (int i = 0; i < 4; ++i) {
                ushort4_t v4;
                v4.x = f2bf(fl[it * 4 + 0][i]);
                v4.y = f2bf(fl[it * 4 + 1][i]);
                v4.z = f2bf(fl[it * 4 + 2][i]);
                v4.w = f2bf(fl[it * 4 + 3][i]);
                *(ushort4_t*)(dst + i * LDS_STRIDE) = v4;
            }
        }
    };

    // hoisted A fragments (wave w covers output channels [w*48, w*48+48))
    // and bias vectors (accumulator init value: acc[tt][pt][r] starts at bias)
    short8  a[3][6];
    floatx4 bo4[3];
    #pragma unroll
    for (int t = 0; t < 3; ++t) {
        const int ot = w * 3 + t;
        const unsigned short* arow = Mb + (ot * 16 + n) * CDIM + q * 8;
        #pragma unroll
        for (int ks = 0; ks < 6; ++ks)        // A[m=lane&15][k=quad*8+j]
            a[t][ks] = *(const short8*)(arow + ks * 32);
        bo4[t] = *(const floatx4*)(bias + ot * 16 + q * 4);
    }

    floatx4 fl[12];

    // prologue: stage tile 0, then issue tile 1's loads and keep them in
    // flight across the barrier (counted vmcnt, not a full drain).
    load_tile(tile0, fl);
    stage_tile(0, fl);              // compiler-inserted vmcnt wait for fl
    load_tile(tile0 + 1, fl);       // 12 loads outstanding from here on
    asm volatile("s_waitcnt vmcnt(12) lgkmcnt(0)" ::: "memory");
    __builtin_amdgcn_s_barrier();
    __builtin_amdgcn_sched_barrier(0);

    #pragma unroll
    for (int t = 0; t < T_TILES; ++t) {
        const int cur = t & 1;

        // compute tile t from Xl[cur]; acc initialized with the bias vector
        floatx4 acc[3][4];
        #pragma unroll
        for (int tt = 0; tt < 3; ++tt)
            #pragma unroll
            for (int pt = 0; pt < 4; ++pt)
                acc[tt][pt] = bo4[tt];

        #pragma unroll
        for (int pt = 0; pt < 4; ++pt) {
            const int row = pt * 16 + n;
            const int sw  = ((row >> 2) & 7) << 3;
            const unsigned short* rbase = &Xl[cur][row * LDS_STRIDE];
            short8 bfr[6];
            #pragma unroll
            for (int ks = 0; ks < 6; ++ks)    // B[k=quad*8+j][n=lane&15]
                bfr[ks] = *(const short8*)(rbase + ((q * 8 + ks * 32) ^ sw));
            #pragma unroll
            for (int tt = 0; tt < 3; ++tt)
                #pragma unroll
                for (int ks = 0; ks < 6; ++ks)
                    acc[tt][pt] = __builtin_amdgcn_mfma_f32_16x16x32_bf16(
                        a[tt][ks], bfr[ks], acc[tt][pt], 0, 0, 0);
        }

        // stage tile t+1 now (consumes fl; the only outstanding vmem ops are
        // fl's 12 loads, issued a full tile ago -> near-zero wait)
        if (t + 1 < T_TILES)
            stage_tile(cur ^ 1, fl);

        // store tile t: D row = q*4 + r, col = n  (bias already in acc)
        {
            const int tile = tile0 + t;
            float* ob = out + (size_t)(tile >> 8) * (CDIM * HWPX)
                            + ((tile & 255) << 6);
            #pragma unroll
            for (int tt = 0; tt < 3; ++tt) {
                #pragma unroll
                for (int r = 0; r < 4; ++r) {
                    const int o = (w * 3 + tt) * 16 + q * 4 + r;
                    float* orow = ob + (size_t)o * HWPX + n;
                    #pragma unroll
                    for (int pt = 0; pt < 4; ++pt)
                        orow[pt * 16] = acc[tt][pt][r];
                }
            }
        }

        // prefetch tile t+2 AFTER the stores: in-order vmcnt(12) then drains
        // all 48 stores (write flow control, the v3 lesson) while keeping
        // these 12 loads in flight across the barrier.
        if (t + 2 < T_TILES)
            load_tile(tile0 + t + 2, fl);

        if (t + 1 < T_TILES) {
            asm volatile("s_waitcnt vmcnt(12) lgkmcnt(0)" ::: "memory");
            __builtin_amdgcn_s_barrier();
            __builtin_amdgcn_sched_barrier(0);
        }
    }
}

extern "C" void kernel_launch(void* const* d_in, const int* in_sizes, int n_in,
                              void* d_out, int out_size, void* d_ws, size_t ws_size,
                              hipStream_t stream) {
    const float* x      = (const float*)d_in[0];
    const float* w_qkv  = (const float*)d_in[1];
    const float* b_qkv  = (const float*)d_in[2];
    // d_in[3] = w_attn, d_in[4] = b_attn: mathematically unused (softmax sums to 1)
    const float* w_proj = (const float*)d_in[5];
    const float* b_proj = (const float*)d_in[6];
    float* out = (float*)d_out;

    unsigned short* Mb = (unsigned short*)d_ws;                       // 192*192 bf16
    float* bias = (float*)((char*)d_ws + CDIM * CDIM * sizeof(unsigned short));

    const int B = in_sizes[0] / (CDIM * HWPX);  // 8

    prep_kernel<<<CDIM, CDIM, 0, stream>>>(w_qkv, b_qkv, w_proj, b_proj, Mb, bias);
    fused_kernel<<<(B * 256) / T_TILES, 256, 0, stream>>>(x, Mb, bias, out);
}

// Round 5
// 201.711 us; speedup vs baseline: 1.1977x; 1.0348x over previous
//
#include <hip/hip_runtime.h>
#include <stdint.h>
#include <stddef.h>

// Reference collapse:
//   softmax over k sums to 1 and the einsum applies it pointwise to v,
//   so out = conv1x1(conv1x1(x, W_v, b_v), W_proj, b_proj)
//          = (W_proj @ W_v) @ x  + (W_proj @ b_v + b_proj)
// One 192x192 bf16-MFMA GEMM over 8*16384 pixels.
//
// ROOFLINE MODEL (corrected in v6): the binding resource is CU-side vector
// memory throughput, not HBM bytes. Compulsory traffic = 201.3MB (x, fp32)
// + 201.3MB (out, fp32) = 402.6MB crossing the CU<->L2<->fabric path every
// iteration; the L3 absorbs ~60% at the HBM boundary but gives no rate
// advantage (m13 copy ceiling 6.29 TB/s counts read+write). Floor = 64.0us.
// v2 (this structure) measured 65.2us = 98% of floor; all pipelining
// variants (v3 lazy-drain, v5 counted-vmcnt) were neutral or negative —
// only TRAFFIC changes moved the time (v3/v4 inflated writes via L2
// dirty-line thrash at 3 blocks/CU).
//
// v6 = v2 structure (T_TILES=4, grid 512, 2 blocks/CU, full __syncthreads
// drains = write flow control, exactly 98.3MB writes) + the two verified
// micro-wins: XOR LDS swizzle (bank conflicts 3.54M->1.18M) and bias
// folded into the accumulator init.

#define CDIM 192
#define HWPX 16384
#define LDS_STRIDE 200  // 192 + 8 pad (ushorts)
#define T_TILES 4       // tiles per block; grid = 2048/4 = 512 = 2 blocks/CU

typedef __attribute__((ext_vector_type(8))) short short8;
typedef __attribute__((ext_vector_type(4))) float floatx4;
typedef __attribute__((ext_vector_type(4))) unsigned short ushort4_t;

__device__ __forceinline__ unsigned short f2bf(float f) {
    union { float f; unsigned int u; } v; v.f = f;
    unsigned int r = (v.u + 0x7FFFu + ((v.u >> 16) & 1u)) >> 16;  // RTNE
    return (unsigned short)r;
}

// ---- prep: M = W_proj @ W_v (bf16), bias = W_proj @ b_v + b_proj ----
__global__ __launch_bounds__(192) void prep_kernel(
    const float* __restrict__ w_qkv, const float* __restrict__ b_qkv,
    const float* __restrict__ w_proj, const float* __restrict__ b_proj,
    unsigned short* __restrict__ Mb, float* __restrict__ bias)
{
    const int o = blockIdx.x, c = threadIdx.x;
    const float* wpr = w_proj + o * CDIM;
    const float* wv  = w_qkv + 2 * CDIM * CDIM;  // v-rows of w_qkv
    float acc = 0.f;
    #pragma unroll 32
    for (int k = 0; k < CDIM; ++k)
        acc = fmaf(wpr[k], wv[k * CDIM + c], acc);
    Mb[o * CDIM + c] = f2bf(acc);

    __shared__ float red[CDIM];
    red[c] = wpr[c] * b_qkv[2 * CDIM + c];
    __syncthreads();
    if (c < 64) {
        float v = red[c] + red[c + 64] + red[c + 128];
        #pragma unroll
        for (int off = 32; off > 0; off >>= 1) v += __shfl_down(v, off);
        if (c == 0) bias[o] = v + b_proj[o];
    }
}

// ---- main: out[b, :, p0:p0+64] = M @ x[b, :, p0:p0+64] + bias ----
__global__ __launch_bounds__(256, 2) void fused_kernel(
    const float* __restrict__ x,
    const unsigned short* __restrict__ Mb,
    const float* __restrict__ bias,
    float* __restrict__ out)
{
    __shared__ __align__(16) unsigned short Xl[2][64 * LDS_STRIDE];  // 2 x 25.6 KB

    const int tid  = threadIdx.x;
    const int lane = tid & 63;
    const int w    = tid >> 6;    // wave 0..3
    const int n    = lane & 15;   // MFMA n / m-lane index
    const int q    = lane >> 4;   // MFMA quad

    // staging geometry: p4 = tid&15 (4-px group), cg0 = tid>>4 (4-ch group base)
    const int p4  = tid & 15;
    const int cg0 = tid >> 4;

    const int tile0 = blockIdx.x * T_TILES;

    // issue the 12 float4 loads of one tile into registers (no wait here)
    auto load_tile = [&](int tile, floatx4* fl) {
        const float* xb = x + (size_t)(tile >> 8) * (CDIM * HWPX)
                            + ((tile & 255) << 6);
        const float* src0 = xb + (size_t)(cg0 * 4) * HWPX + p4 * 4;
        #pragma unroll
        for (int it = 0; it < 3; ++it) {
            const float* src = src0 + (size_t)(it * 64) * HWPX;
            #pragma unroll
            for (int j = 0; j < 4; ++j)
                fl[it * 4 + j] = *(const floatx4*)(src + (size_t)j * HWPX);
        }
    };

    // convert fp32 -> bf16 and write transposed [p][c^swz] into LDS buffer.
    // swizzle: 16B-block index XORed with (row>>2)&7; row = p4*4+i so the
    // swizzle operand is p4 (constant across i) -> compute column once.
    auto stage_tile = [&](int buf, const floatx4* fl) {
        const int sw = (p4 & 7) << 3;   // (row>>2)&7 == p4&7, in ushort units
        #pragma unroll
        for (int it = 0; it < 3; ++it) {
            unsigned short* dst =
                &Xl[buf][(p4 * 4) * LDS_STRIDE + (((it * 16 + cg0) * 4) ^ sw)];
            #pragma unroll
            for (int i = 0; i < 4; ++i) {
                ushort4_t v4;
                v4.x = f2bf(fl[it * 4 + 0][i]);
                v4.y = f2bf(fl[it * 4 + 1][i]);
                v4.z = f2bf(fl[it * 4 + 2][i]);
                v4.w = f2bf(fl[it * 4 + 3][i]);
                *(ushort4_t*)(dst + i * LDS_STRIDE) = v4;
            }
        }
    };

    // hoisted A fragments (wave w covers output channels [w*48, w*48+48))
    // and bias vectors (accumulator init value: acc[tt][pt] starts at bias)
    short8  a[3][6];
    floatx4 bo4[3];
    #pragma unroll
    for (int t = 0; t < 3; ++t) {
        const int ot = w * 3 + t;
        const unsigned short* arow = Mb + (ot * 16 + n) * CDIM + q * 8;
        #pragma unroll
        for (int ks = 0; ks < 6; ++ks)        // A[m=lane&15][k=quad*8+j]
            a[t][ks] = *(const short8*)(arow + ks * 32);
        bo4[t] = *(const floatx4*)(bias + ot * 16 + q * 4);
    }

    floatx4 fl[12];

    // prologue: stage tile 0
    load_tile(tile0, fl);
    stage_tile(0, fl);
    __syncthreads();

    #pragma unroll
    for (int t = 0; t < T_TILES; ++t) {
        const int cur = t & 1;

        // issue next tile's loads FIRST — HBM latency hides under MFMA+stores
        if (t + 1 < T_TILES)
            load_tile(tile0 + t + 1, fl);

        // compute tile t from Xl[cur]; acc initialized with the bias vector
        floatx4 acc[3][4];
        #pragma unroll
        for (int tt = 0; tt < 3; ++tt)
            #pragma unroll
            for (int pt = 0; pt < 4; ++pt)
                acc[tt][pt] = bo4[tt];

        #pragma unroll
        for (int pt = 0; pt < 4; ++pt) {
            const int row = pt * 16 + n;
            const int sw  = ((row >> 2) & 7) << 3;
            const unsigned short* rbase = &Xl[cur][row * LDS_STRIDE];
            short8 bfr[6];
            #pragma unroll
            for (int ks = 0; ks < 6; ++ks)    // B[k=quad*8+j][n=lane&15]
                bfr[ks] = *(const short8*)(rbase + ((q * 8 + ks * 32) ^ sw));
            #pragma unroll
            for (int tt = 0; tt < 3; ++tt)
                #pragma unroll
                for (int ks = 0; ks < 6; ++ks)
                    acc[tt][pt] = __builtin_amdgcn_mfma_f32_16x16x32_bf16(
                        a[tt][ks], bfr[ks], acc[tt][pt], 0, 0, 0);
        }

        // store tile t: D row = q*4 + r, col = n  (bias already in acc)
        {
            const int tile = tile0 + t;
            float* ob = out + (size_t)(tile >> 8) * (CDIM * HWPX)
                            + ((tile & 255) << 6);
            #pragma unroll
            for (int tt = 0; tt < 3; ++tt) {
                #pragma unroll
                for (int r = 0; r < 4; ++r) {
                    const int o = (w * 3 + tt) * 16 + q * 4 + r;
                    float* orow = ob + (size_t)o * HWPX + n;
                    #pragma unroll
                    for (int pt = 0; pt < 4; ++pt)
                        orow[pt * 16] = acc[tt][pt][r];
                }
            }
        }

        // consume the prefetch, then full __syncthreads(): the vmcnt(0)
        // drain doubles as store-burst flow control (v3 lesson) — and since
        // we are throughput-bound, not latency-bound (v5 lesson), the drain
        // costs nothing.
        if (t + 1 < T_TILES)
            stage_tile(cur ^ 1, fl);

        __syncthreads();
    }
}

extern "C" void kernel_launch(void* const* d_in, const int* in_sizes, int n_in,
                              void* d_out, int out_size, void* d_ws, size_t ws_size,
                              hipStream_t stream) {
    const float* x      = (const float*)d_in[0];
    const float* w_qkv  = (const float*)d_in[1];
    const float* b_qkv  = (const float*)d_in[2];
    // d_in[3] = w_attn, d_in[4] = b_attn: mathematically unused (softmax sums to 1)
    const float* w_proj = (const float*)d_in[5];
    const float* b_proj = (const float*)d_in[6];
    float* out = (float*)d_out;

    unsigned short* Mb = (unsigned short*)d_ws;                       // 192*192 bf16
    float* bias = (float*)((char*)d_ws + CDIM * CDIM * sizeof(unsigned short));

    const int B = in_sizes[0] / (CDIM * HWPX);  // 8

    prep_kernel<<<CDIM, CDIM, 0, stream>>>(w_qkv, b_qkv, w_proj, b_proj, Mb, bias);
    fused_kernel<<<(B * 256) / T_TILES, 256, 0, stream>>>(x, Mb, bias, out);
}

// Round 7
// 197.979 us; speedup vs baseline: 1.2203x; 1.0188x over previous
//
#include <hip/hip_runtime.h>
#include <stdint.h>
#include <stddef.h>

// Reference collapse:
//   softmax over k sums to 1 and the einsum applies it pointwise to v,
//   so out = conv1x1(conv1x1(x, W_v, b_v), W_proj, b_proj)
//          = (W_proj @ W_v) @ x  + (W_proj @ b_v + b_proj)
// One 192x192 bf16-MFMA GEMM over 8*16384 pixels.
//
// ROOFLINE (corrected in v7): x = 100.7MB, out = 100.7MB -> compulsory
// CU-side traffic 201.3MB. Floor = 201.3/6.29TB/s ~= 32us. v6 = 66us =
// 2.06x floor, 3.0 TB/s CU-side, with MFMA 5% / VALU 4% / HBM 29% /
// occupancy 15.7% — nothing saturated => still concurrency-bound at
// 8 waves/CU.
//
// v7 (resubmit — round 6 bench died on container infra, not the kernel):
// raise occupancy. T_TILES=2, grid 1024 -> 3 blocks resident/CU
// (LDS-capped), 12 waves/CU. This is v4's geometry WITHOUT the
// __launch_bounds__(256,3) VGPR squeeze: v3/v4's traffic inflation was
// scratch SPILLS at VGPR=84 (live set ~130), not L2 dirty thrash —
// v1 ran ~6 blocks/CU one-shot with exactly clean traffic. Keep
// (256,2) = proven 128 VGPR, zero spill.

#define CDIM 192
#define HWPX 16384
#define LDS_STRIDE 200  // 192 + 8 pad (ushorts)
#define T_TILES 2       // tiles per block; grid = 2048/2 = 1024

typedef __attribute__((ext_vector_type(8))) short short8;
typedef __attribute__((ext_vector_type(4))) float floatx4;
typedef __attribute__((ext_vector_type(4))) unsigned short ushort4_t;

__device__ __forceinline__ unsigned short f2bf(float f) {
    union { float f; unsigned int u; } v; v.f = f;
    unsigned int r = (v.u + 0x7FFFu + ((v.u >> 16) & 1u)) >> 16;  // RTNE
    return (unsigned short)r;
}

// ---- prep: M = W_proj @ W_v (bf16), bias = W_proj @ b_v + b_proj ----
__global__ __launch_bounds__(192) void prep_kernel(
    const float* __restrict__ w_qkv, const float* __restrict__ b_qkv,
    const float* __restrict__ w_proj, const float* __restrict__ b_proj,
    unsigned short* __restrict__ Mb, float* __restrict__ bias)
{
    const int o = blockIdx.x, c = threadIdx.x;
    const float* wpr = w_proj + o * CDIM;
    const float* wv  = w_qkv + 2 * CDIM * CDIM;  // v-rows of w_qkv
    float acc = 0.f;
    #pragma unroll 32
    for (int k = 0; k < CDIM; ++k)
        acc = fmaf(wpr[k], wv[k * CDIM + c], acc);
    Mb[o * CDIM + c] = f2bf(acc);

    __shared__ float red[CDIM];
    red[c] = wpr[c] * b_qkv[2 * CDIM + c];
    __syncthreads();
    if (c < 64) {
        float v = red[c] + red[c + 64] + red[c + 128];
        #pragma unroll
        for (int off = 32; off > 0; off >>= 1) v += __shfl_down(v, off);
        if (c == 0) bias[o] = v + b_proj[o];
    }
}

// ---- main: out[b, :, p0:p0+64] = M @ x[b, :, p0:p0+64] + bias ----
__global__ __launch_bounds__(256, 2) void fused_kernel(
    const float* __restrict__ x,
    const unsigned short* __restrict__ Mb,
    const float* __restrict__ bias,
    float* __restrict__ out)
{
    __shared__ __align__(16) unsigned short Xl[2][64 * LDS_STRIDE];  // 2 x 25.6 KB

    const int tid  = threadIdx.x;
    const int lane = tid & 63;
    const int w    = tid >> 6;    // wave 0..3
    const int n    = lane & 15;   // MFMA n / m-lane index
    const int q    = lane >> 4;   // MFMA quad

    // staging geometry: p4 = tid&15 (4-px group), cg0 = tid>>4 (4-ch group base)
    const int p4  = tid & 15;
    const int cg0 = tid >> 4;

    const int tile0 = blockIdx.x * T_TILES;

    // issue the 12 float4 loads of one tile into registers (no wait here)
    auto load_tile = [&](int tile, floatx4* fl) {
        const float* xb = x + (size_t)(tile >> 8) * (CDIM * HWPX)
                            + ((tile & 255) << 6);
        const float* src0 = xb + (size_t)(cg0 * 4) * HWPX + p4 * 4;
        #pragma unroll
        for (int it = 0; it < 3; ++it) {
            const float* src = src0 + (size_t)(it * 64) * HWPX;
            #pragma unroll
            for (int j = 0; j < 4; ++j)
                fl[it * 4 + j] = *(const floatx4*)(src + (size_t)j * HWPX);
        }
    };

    // convert fp32 -> bf16 and write transposed [p][c^swz] into LDS buffer.
    // swizzle: 16B-block index XORed with (row>>2)&7; row = p4*4+i so the
    // swizzle operand is p4 (constant across i) -> compute column once.
    auto stage_tile = [&](int buf, const floatx4* fl) {
        const int sw = (p4 & 7) << 3;   // (row>>2)&7 == p4&7, in ushort units
        #pragma unroll
        for (int it = 0; it < 3; ++it) {
            unsigned short* dst =
                &Xl[buf][(p4 * 4) * LDS_STRIDE + (((it * 16 + cg0) * 4) ^ sw)];
            #pragma unroll
            for (int i = 0; i < 4; ++i) {
                ushort4_t v4;
                v4.x = f2bf(fl[it * 4 + 0][i]);
                v4.y = f2bf(fl[it * 4 + 1][i]);
                v4.z = f2bf(fl[it * 4 + 2][i]);
                v4.w = f2bf(fl[it * 4 + 3][i]);
                *(ushort4_t*)(dst + i * LDS_STRIDE) = v4;
            }
        }
    };

    // hoisted A fragments (wave w covers output channels [w*48, w*48+48))
    // and bias vectors (accumulator init value: acc[tt][pt] starts at bias)
    short8  a[3][6];
    floatx4 bo4[3];
    #pragma unroll
    for (int t = 0; t < 3; ++t) {
        const int ot = w * 3 + t;
        const unsigned short* arow = Mb + (ot * 16 + n) * CDIM + q * 8;
        #pragma unroll
        for (int ks = 0; ks < 6; ++ks)        // A[m=lane&15][k=quad*8+j]
            a[t][ks] = *(const short8*)(arow + ks * 32);
        bo4[t] = *(const floatx4*)(bias + ot * 16 + q * 4);
    }

    floatx4 fl[12];

    // prologue: stage tile 0
    load_tile(tile0, fl);
    stage_tile(0, fl);
    __syncthreads();

    #pragma unroll
    for (int t = 0; t < T_TILES; ++t) {
        const int cur = t & 1;

        // issue next tile's loads FIRST — HBM latency hides under MFMA+stores
        if (t + 1 < T_TILES)
            load_tile(tile0 + t + 1, fl);

        // compute tile t from Xl[cur]; acc initialized with the bias vector
        floatx4 acc[3][4];
        #pragma unroll
        for (int tt = 0; tt < 3; ++tt)
            #pragma unroll
            for (int pt = 0; pt < 4; ++pt)
                acc[tt][pt] = bo4[tt];

        #pragma unroll
        for (int pt = 0; pt < 4; ++pt) {
            const int row = pt * 16 + n;
            const int sw  = ((row >> 2) & 7) << 3;
            const unsigned short* rbase = &Xl[cur][row * LDS_STRIDE];
            short8 bfr[6];
            #pragma unroll
            for (int ks = 0; ks < 6; ++ks)    // B[k=quad*8+j][n=lane&15]
                bfr[ks] = *(const short8*)(rbase + ((q * 8 + ks * 32) ^ sw));
            #pragma unroll
            for (int tt = 0; tt < 3; ++tt)
                #pragma unroll
                for (int ks = 0; ks < 6; ++ks)
                    acc[tt][pt] = __builtin_amdgcn_mfma_f32_16x16x32_bf16(
                        a[tt][ks], bfr[ks], acc[tt][pt], 0, 0, 0);
        }

        // store tile t: D row = q*4 + r, col = n  (bias already in acc)
        {
            const int tile = tile0 + t;
            float* ob = out + (size_t)(tile >> 8) * (CDIM * HWPX)
                            + ((tile & 255) << 6);
            #pragma unroll
            for (int tt = 0; tt < 3; ++tt) {
                #pragma unroll
                for (int r = 0; r < 4; ++r) {
                    const int o = (w * 3 + tt) * 16 + q * 4 + r;
                    float* orow = ob + (size_t)o * HWPX + n;
                    #pragma unroll
                    for (int pt = 0; pt < 4; ++pt)
                        orow[pt * 16] = acc[tt][pt][r];
                }
            }
        }

        // consume the prefetch, then full __syncthreads() (store drain =
        // write flow control; cheap since other resident blocks keep the
        // memory system busy at 12 waves/CU).
        if (t + 1 < T_TILES)
            stage_tile(cur ^ 1, fl);

        __syncthreads();
    }
}

extern "C" void kernel_launch(void* const* d_in, const int* in_sizes, int n_in,
                              void* d_out, int out_size, void* d_ws, size_t ws_size,
                              hipStream_t stream) {
    const float* x      = (const float*)d_in[0];
    const float* w_qkv  = (const float*)d_in[1];
    const float* b_qkv  = (const float*)d_in[2];
    // d_in[3] = w_attn, d_in[4] = b_attn: mathematically unused (softmax sums to 1)
    const float* w_proj = (const float*)d_in[5];
    const float* b_proj = (const float*)d_in[6];
    float* out = (float*)d_out;

    unsigned short* Mb = (unsigned short*)d_ws;                       // 192*192 bf16
    float* bias = (float*)((char*)d_ws + CDIM * CDIM * sizeof(unsigned short));

    const int B = in_sizes[0] / (CDIM * HWPX);  // 8

    prep_kernel<<<CDIM, CDIM, 0, stream>>>(w_qkv, b_qkv, w_proj, b_proj, Mb, bias);
    fused_kernel<<<(B * 256) / T_TILES, 256, 0, stream>>>(x, Mb, bias, out);
}